// Round 4
// baseline (261.851 us; speedup 1.0000x reference)
//
#include <hip/hip_runtime.h>

// points [B=32, N=8192, 3] f32. FPS -> K=128 centers/batch (start 0);
// KNN -> P=32 nearest per center, ascending d2, ties by lower index.
// d_out is FLOAT32, flat concat: [idx B*K*P | centers B*K*3].
//
// FUSED producer->consumer, R4: 224 blocks x 1024 threads, 128 KiB LDS
// (=> hard 1 block/CU => all 224 co-resident on 256 CUs).
//   blocks 0..31   : FPS, 8 pts/thread (1024 thr). Compute phase per step
//                    halves vs 512-thr (R3 counters: FPS step ~2.5k cyc,
//                    ~800 of it 16-pt compute serialized 2 waves/SIMD).
//                    Thread 0 publishes each center to d_ws immediately
//                    (relaxed agent-scope). BAR_LDS (no vmcnt drain).
//   blocks 32..223 : 6 KNN blocks/batch, 16 waves = 4/SIMD (R3: KNN ~50%
//                    latency-stalled at 2 waves/SIMD). Waves CLAIM centers
//                    from a per-batch atomic counter (claim order = arrival
//                    order, auto balanced, ~solo tail on the last center),
//                    then spin on sentinel-validated words (0xFFFFFFFF =
//                    NaN, impossible for finite coords).
// Bit-parity: identical per-(point,center) arithmetic; min/argmax over the
// same exact u64 key sets regardless of thread partition. Deadlock-free:
// one-way dependency + guaranteed co-residency.
#define BB 32
#define NN 8192
#define KK 128
#define PP 32
#define IDX_COUNT (BB * KK * PP)      // 131072
#define XCHG_WORDS (BB * KK * 3)      // 12288 center words
#define CLEAR_WORDS (XCHG_WORDS + BB) // + 32 claim counters
#define KNN_PER_B 6
#define NBLK (BB + BB * KNN_PER_B)    // 224

// ---- DPP wave64 reductions (VALU-only) ------------------------------------
// row_shr:1/2/4/8 then row_bcast15/31; lane 63 holds the result.
#define DPP_RED_U64(v, CMP)                                                   \
    {                                                                         \
        _Pragma("unroll")                                                     \
        for (int s = 0; s < 6; ++s) {                                         \
            const int ctrl = (s == 0) ? 0x111 : (s == 1) ? 0x112 :            \
                             (s == 2) ? 0x114 : (s == 3) ? 0x118 :            \
                             (s == 4) ? 0x142 : 0x143;                        \
            unsigned lo = (unsigned)v, hi = (unsigned)(v >> 32);              \
            unsigned slo, shi;                                                \
            switch (ctrl) {                                                   \
            case 0x111:                                                       \
                slo = (unsigned)__builtin_amdgcn_update_dpp((int)lo, (int)lo, 0x111, 0xf, 0xf, false); \
                shi = (unsigned)__builtin_amdgcn_update_dpp((int)hi, (int)hi, 0x111, 0xf, 0xf, false); break; \
            case 0x112:                                                       \
                slo = (unsigned)__builtin_amdgcn_update_dpp((int)lo, (int)lo, 0x112, 0xf, 0xf, false); \
                shi = (unsigned)__builtin_amdgcn_update_dpp((int)hi, (int)hi, 0x112, 0xf, 0xf, false); break; \
            case 0x114:                                                       \
                slo = (unsigned)__builtin_amdgcn_update_dpp((int)lo, (int)lo, 0x114, 0xf, 0xf, false); \
                shi = (unsigned)__builtin_amdgcn_update_dpp((int)hi, (int)hi, 0x114, 0xf, 0xf, false); break; \
            case 0x118:                                                       \
                slo = (unsigned)__builtin_amdgcn_update_dpp((int)lo, (int)lo, 0x118, 0xf, 0xf, false); \
                shi = (unsigned)__builtin_amdgcn_update_dpp((int)hi, (int)hi, 0x118, 0xf, 0xf, false); break; \
            case 0x142:                                                       \
                slo = (unsigned)__builtin_amdgcn_update_dpp((int)lo, (int)lo, 0x142, 0xf, 0xf, false); \
                shi = (unsigned)__builtin_amdgcn_update_dpp((int)hi, (int)hi, 0x142, 0xf, 0xf, false); break; \
            default:                                                          \
                slo = (unsigned)__builtin_amdgcn_update_dpp((int)lo, (int)lo, 0x143, 0xf, 0xf, false); \
                shi = (unsigned)__builtin_amdgcn_update_dpp((int)hi, (int)hi, 0x143, 0xf, 0xf, false); break; \
            }                                                                 \
            const unsigned long long sv = ((unsigned long long)shi << 32) | slo; \
            if (sv CMP v) v = sv;                                             \
        }                                                                     \
    }

__device__ __forceinline__ unsigned long long readlane63_u64(unsigned long long v) {
    const unsigned lo = (unsigned)__builtin_amdgcn_readlane((int)(unsigned)v, 63);
    const unsigned hi = (unsigned)__builtin_amdgcn_readlane((int)(unsigned)(v >> 32), 63);
    return ((unsigned long long)hi << 32) | lo;
}

// Relaxed agent-scope word publish/poll. Finite-float bit patterns can never
// be 0xFFFFFFFF => sentinel self-validates each word; no ordering needed.
__device__ __forceinline__ void publish_word(unsigned* p, float v) {
    __hip_atomic_store(p, __float_as_uint(v), __ATOMIC_RELAXED,
                       __HIP_MEMORY_SCOPE_AGENT);
}
__device__ __forceinline__ float poll_word(const unsigned* p) {
    unsigned u = __hip_atomic_load(p, __ATOMIC_RELAXED, __HIP_MEMORY_SCOPE_AGENT);
    while (u == 0xFFFFFFFFu) {
        __builtin_amdgcn_s_sleep(8);   // ~512 cyc backoff
        u = __hip_atomic_load(p, __ATOMIC_RELAXED, __HIP_MEMORY_SCOPE_AGENT);
    }
    return __uint_as_float(u);
}

// Raw barrier with LDS-only drain (no vmcnt): publish stores stay in flight.
// Valid: the only cross-wave data at this barrier is LDS (wkf double-buffered).
#define BAR_LDS() asm volatile("s_waitcnt lgkmcnt(0)\n\ts_barrier" ::: "memory")

#define CACHE_INS(kk, m1, m2, m3, m4)                                   \
    {                                                                   \
        const bool c1 = (kk) < m1, c2 = (kk) < m2,                      \
                   c3 = (kk) < m3, c4 = (kk) < m4;                      \
        m4 = c3 ? m3 : (c4 ? (kk) : m4);                                \
        m3 = c2 ? m2 : (c3 ? (kk) : m3);                                \
        m2 = c1 ? m1 : (c2 ? (kk) : m2);                                \
        m1 = c1 ? (kk) : m1;                                            \
    }

__global__ __launch_bounds__(1024) void clear_kernel(unsigned* __restrict__ xchg) {
    const int i = blockIdx.x * 1024 + threadIdx.x;   // grid 13 x 1024
    if (i < XCHG_WORDS) xchg[i] = 0xFFFFFFFFu;       // center sentinels
    else if (i < CLEAR_WORDS) xchg[i] = 0u;          // claim counters
}

__global__ __launch_bounds__(1024) void fused_kernel(
    const float* __restrict__ pts, float* __restrict__ out,
    unsigned* __restrict__ xchg)
{
#pragma clang fp contract(off)
    // 128 KiB raw LDS => hard 1 block/CU (residency proof: 224 <= 256 CUs).
    __shared__ __align__(16) unsigned char smem_raw[131072];
    const int t = threadIdx.x;
    const int lane = t & 63, wid = t >> 6;

    if (blockIdx.x < BB) {
        // ------------------------- FPS producer --------------------------
        const int b = blockIdx.x;
        const float* p = pts + (size_t)b * NN * 3;
        float* pts3 = (float*)smem_raw;                        // 96 KB
        float* cbuf = (float*)(smem_raw + 98304);              // 1.5 KB
        unsigned long long* wkf =
            (unsigned long long*)(smem_raw + 98304 + 1536);    // [2][16]

        if (t == 0) {   // publish center 0 (= point 0) immediately
            unsigned* dst = xchg + (unsigned)b * KK * 3u;
            publish_word(dst + 0, p[0]);
            publish_word(dst + 1, p[1]);
            publish_word(dst + 2, p[2]);
        }

        float px[8], py[8], pz[8], mind[8];
#pragma unroll
        for (int i = 0; i < 8; ++i) {
            const int idx = t + i * 1024;
            const float x = p[idx * 3 + 0], y = p[idx * 3 + 1], z = p[idx * 3 + 2];
            px[i] = x; py[i] = y; pz[i] = z; mind[i] = __builtin_inff();
            pts3[idx * 3 + 0] = x; pts3[idx * 3 + 1] = y; pts3[idx * 3 + 2] = z;
        }
        __syncthreads();   // staging barrier (full drain fine, once)

        float lx = pts3[0], ly = pts3[1], lz = pts3[2];
        if (t == 0) { cbuf[0] = lx; cbuf[1] = ly; cbuf[2] = lz; }

        for (int k = 0; k < KK - 1; ++k) {       // 127 serial steps
            float best = -1.0f; unsigned bidx = 0;
#pragma unroll
            for (int i = 0; i < 8; ++i) {
                const float dx = px[i] - lx, dy = py[i] - ly, dz = pz[i] - lz;
                const float d = (dx * dx + dy * dy) + dz * dz;
                const float m = mind[i] < d ? mind[i] : d;
                mind[i] = m;
                if (m > best) { best = m; bidx = (unsigned)(t + i * 1024); }
            }
            union { float f; unsigned u; } cv; cv.f = best;   // best >= 0
            unsigned long long key = ((unsigned long long)cv.u << 32)
                                   | (0xFFFFFFFFu - bidx);    // low-idx tie-break
            DPP_RED_U64(key, >);                  // lane 63 authoritative
            if (lane == 63) wkf[(k & 1) * 16 + wid] = key;
            BAR_LDS();   // LDS-only drain: publish stores never stall the chain
            unsigned long long w = wkf[(k & 1) * 16];
#pragma unroll
            for (int i = 1; i < 16; ++i) {
                const unsigned long long o = wkf[(k & 1) * 16 + i];
                if (o > w) w = o;
            }
            const unsigned last = 0xFFFFFFFFu - (unsigned)(w & 0xFFFFFFFFu);
            lx = pts3[last * 3 + 0];              // broadcast reads
            ly = pts3[last * 3 + 1];
            lz = pts3[last * 3 + 2];
            if (t == 0) {
                cbuf[(k + 1) * 3 + 0] = lx;
                cbuf[(k + 1) * 3 + 1] = ly;
                cbuf[(k + 1) * 3 + 2] = lz;
                unsigned* dst = xchg + ((unsigned)b * KK + (unsigned)(k + 1)) * 3u;
                publish_word(dst + 0, lx);        // fire-and-forget (relaxed)
                publish_word(dst + 1, ly);
                publish_word(dst + 2, lz);
            }
        }
        __syncthreads();
        if (t < KK * 3)
            out[IDX_COUNT + b * (KK * 3) + t] = cbuf[t];
    } else {
        // ------------------------- KNN consumer --------------------------
        const int blk = blockIdx.x - BB;          // 0..191
        const int b = blk / KNN_PER_B;            // 6 blocks/batch
        float4* sp = (float4*)smem_raw;           // 128 KB
        const float* p = pts + (size_t)b * NN * 3;
#pragma unroll
        for (int i = 0; i < 8; ++i) {
            const int idx = t + i * 1024;
            const float x = p[idx * 3 + 0], y = p[idx * 3 + 1], z = p[idx * 3 + 2];
            sp[idx] = make_float4(x, y, z, (x * x + y * y) + z * z);
        }
        __syncthreads();   // only barrier; afterwards waves run independently

        unsigned* claims = xchg + XCHG_WORDS;     // per-batch center counter
        for (;;) {
            unsigned m = 0;
            if (lane == 0) m = atomicAdd(claims + b, 1u);   // device-scope
            m = (unsigned)__builtin_amdgcn_readfirstlane((int)m);
            if (m >= KK) break;
            const int c = (int)m;

            const unsigned* src = xchg + ((unsigned)b * KK + (unsigned)c) * 3u;
            const float cx = poll_word(src + 0);
            const float cy = poll_word(src + 1);
            const float cz = poll_word(src + 2);
            const float cc = (cx * cx + cy * cy) + cz * cz;

            unsigned long long m1 = ~0ull, m2 = ~0ull, m3 = ~0ull, m4 = ~0ull;
#pragma unroll 4
            for (int i = 0; i < 128; ++i) {
                const int idx = lane + i * 64;
                const float4 q = sp[idx];
                const float dot = (cx * q.x + cy * q.y) + cz * q.z;
                float d2 = (cc + q.w) - (2.0f * dot);
                d2 = d2 + 0.0f;                                   // -0.0 -> +0.0
                union { float f; unsigned u; } cv; cv.f = d2;
                unsigned uu = cv.u;
                uu = (uu & 0x80000000u) ? ~uu : (uu | 0x80000000u); // ordered-uint
                const unsigned long long kk2 =
                    ((unsigned long long)uu << 32) | (unsigned)idx;
                CACHE_INS(kk2, m1, m2, m3, m4);
            }

            float resv = 0.0f;
            for (int j = 0; j < PP; ++j) {
                unsigned long long r = m1;
                DPP_RED_U64(r, <);                    // lane 63 authoritative
                const unsigned long long best = readlane63_u64(r);
                if (lane == j) resv = (float)(unsigned)(best & 0xFFFFFFFFu);
                if (m1 == best) { m1 = m2; m2 = m3; m3 = m4; m4 = ~0ull; }
                if (m1 == ~0ull) {                    // rare exact refill (LDS)
                    for (int i = 0; i < 128; ++i) {
                        const int idx = lane + i * 64;
                        const float4 q = sp[idx];
                        const float dot = (cx * q.x + cy * q.y) + cz * q.z;
                        float d2 = (cc + q.w) - (2.0f * dot);
                        d2 = d2 + 0.0f;
                        union { float f; unsigned u; } cv; cv.f = d2;
                        unsigned uu = cv.u;
                        uu = (uu & 0x80000000u) ? ~uu : (uu | 0x80000000u);
                        const unsigned long long kk2 =
                            ((unsigned long long)uu << 32) | (unsigned)idx;
                        if (kk2 > best) CACHE_INS(kk2, m1, m2, m3, m4);
                    }
                }
            }
            if (lane < PP)
                out[(size_t)(b * KK + c) * PP + lane] = resv;   // 128 B/wave
        }
    }
}

// ------------------------- fallback (ws too small) -------------------------
__global__ __launch_bounds__(512) void fps_kernel(
    const float* __restrict__ pts, float* __restrict__ out)
{
#pragma clang fp contract(off)
    const int b = blockIdx.x;
    const int t = threadIdx.x;
    const float* p = pts + (size_t)b * NN * 3;

    __shared__ float pts3[NN * 3];
    __shared__ float cbuf[KK * 3];
    __shared__ unsigned long long wk[2][8];

    float px[16], py[16], pz[16], mind[16];
#pragma unroll
    for (int i = 0; i < 16; ++i) {
        const int idx = t + i * 512;
        const float x = p[idx * 3 + 0], y = p[idx * 3 + 1], z = p[idx * 3 + 2];
        px[i] = x; py[i] = y; pz[i] = z; mind[i] = __builtin_inff();
        pts3[idx * 3 + 0] = x; pts3[idx * 3 + 1] = y; pts3[idx * 3 + 2] = z;
    }
    __syncthreads();

    float lx = pts3[0], ly = pts3[1], lz = pts3[2];
    if (t == 0) { cbuf[0] = lx; cbuf[1] = ly; cbuf[2] = lz; }
    const int lane = t & 63, wid = t >> 6;

    for (int k = 0; k < KK - 1; ++k) {
        float best = -1.0f; unsigned bidx = 0;
#pragma unroll
        for (int i = 0; i < 16; ++i) {
            const float dx = px[i] - lx, dy = py[i] - ly, dz = pz[i] - lz;
            const float d = (dx * dx + dy * dy) + dz * dz;
            const float m = mind[i] < d ? mind[i] : d;
            mind[i] = m;
            if (m > best) { best = m; bidx = (unsigned)(t + i * 512); }
        }
        union { float f; unsigned u; } cv; cv.f = best;
        unsigned long long key = ((unsigned long long)cv.u << 32)
                               | (0xFFFFFFFFu - bidx);
        DPP_RED_U64(key, >);
        if (lane == 63) wk[k & 1][wid] = key;
        __syncthreads();
        unsigned long long w = wk[k & 1][0];
#pragma unroll
        for (int i = 1; i < 8; ++i) {
            const unsigned long long o = wk[k & 1][i];
            if (o > w) w = o;
        }
        const unsigned last = 0xFFFFFFFFu - (unsigned)(w & 0xFFFFFFFFu);
        lx = pts3[last * 3 + 0];
        ly = pts3[last * 3 + 1];
        lz = pts3[last * 3 + 2];
        if (t == 0) {
            cbuf[(k + 1) * 3 + 0] = lx;
            cbuf[(k + 1) * 3 + 1] = ly;
            cbuf[(k + 1) * 3 + 2] = lz;
        }
    }
    __syncthreads();
    if (t < KK * 3)
        out[IDX_COUNT + b * (KK * 3) + t] = cbuf[t];
}

__global__ __launch_bounds__(1024) void knn_kernel(
    const float* __restrict__ pts, float* __restrict__ out)
{
#pragma clang fp contract(off)
    const int t = threadIdx.x, lane = t & 63, wid = t >> 6;
    const int blk = blockIdx.x;
    const int b = blk >> 3;
    const int bk = b * KK + (blk & 7) * 16 + wid;

    __shared__ float4 sp[NN];
    const float* p = pts + (size_t)b * NN * 3;
#pragma unroll
    for (int i = 0; i < 8; ++i) {
        const int idx = t + i * 1024;
        const float x = p[idx * 3 + 0], y = p[idx * 3 + 1], z = p[idx * 3 + 2];
        sp[idx] = make_float4(x, y, z, (x * x + y * y) + z * z);
    }

    const float cx = out[IDX_COUNT + bk * 3 + 0];
    const float cy = out[IDX_COUNT + bk * 3 + 1];
    const float cz = out[IDX_COUNT + bk * 3 + 2];
    const float cc = (cx * cx + cy * cy) + cz * cz;
    __syncthreads();

    unsigned long long m1 = ~0ull, m2 = ~0ull, m3 = ~0ull, m4 = ~0ull;
#pragma unroll 4
    for (int i = 0; i < 128; ++i) {
        const int idx = lane + i * 64;
        const float4 q = sp[idx];
        const float dot = (cx * q.x + cy * q.y) + cz * q.z;
        float d2 = (cc + q.w) - (2.0f * dot);
        d2 = d2 + 0.0f;
        union { float f; unsigned u; } cv; cv.f = d2;
        unsigned u = cv.u;
        u = (u & 0x80000000u) ? ~u : (u | 0x80000000u);
        const unsigned long long kk =
            ((unsigned long long)u << 32) | (unsigned)idx;
        CACHE_INS(kk, m1, m2, m3, m4);
    }

    float resv = 0.0f;
    for (int j = 0; j < PP; ++j) {
        unsigned long long r = m1;
        DPP_RED_U64(r, <);
        const unsigned long long best = readlane63_u64(r);
        if (lane == j) resv = (float)(unsigned)(best & 0xFFFFFFFFu);
        if (m1 == best) { m1 = m2; m2 = m3; m3 = m4; m4 = ~0ull; }
        if (m1 == ~0ull) {
            for (int i = 0; i < 128; ++i) {
                const int idx = lane + i * 64;
                const float4 q = sp[idx];
                const float dot = (cx * q.x + cy * q.y) + cz * q.z;
                float d2 = (cc + q.w) - (2.0f * dot);
                d2 = d2 + 0.0f;
                union { float f; unsigned u; } cv; cv.f = d2;
                unsigned u = cv.u;
                u = (u & 0x80000000u) ? ~u : (u | 0x80000000u);
                const unsigned long long kk =
                    ((unsigned long long)u << 32) | (unsigned)idx;
                if (kk > best) CACHE_INS(kk, m1, m2, m3, m4);
            }
        }
    }
    if (lane < PP) out[(size_t)bk * PP + lane] = resv;
}

extern "C" void kernel_launch(void* const* d_in, const int* in_sizes, int n_in,
                              void* d_out, int out_size, void* d_ws, size_t ws_size,
                              hipStream_t stream) {
    const float* pts = (const float*)d_in[0];
    float* out = (float*)d_out;   // f32: [idx 131072 | centers 12288]

    if (ws_size >= (size_t)(CLEAR_WORDS * 4)) {
        clear_kernel<<<(CLEAR_WORDS + 1023) / 1024, 1024, 0, stream>>>(
            (unsigned*)d_ws);
        fused_kernel<<<NBLK, 1024, 0, stream>>>(pts, out, (unsigned*)d_ws);
    } else {
        fps_kernel<<<BB, 512, 0, stream>>>(pts, out);
        knn_kernel<<<BB * 8, 1024, 0, stream>>>(pts, out);
    }
}

// Round 7
// 227.510 us; speedup vs baseline: 1.1509x; 1.1509x over previous
//
#include <hip/hip_runtime.h>

// points [B=32, N=8192, 3] f32. FPS -> K=128 centers/batch (start 0);
// KNN -> P=32 nearest per center, ascending d2, ties by lower index.
// d_out is FLOAT32, flat concat: [idx B*K*P | centers B*K*3].
//
// FUSED producer->consumer, R5: 128 blocks x 512 threads, 128 KiB LDS
// (=> hard 1 block/CU; HALF the chip idle => less power => less clock
// throttle on the serial FPS chain — leading theory for the fused-chain
// inflation: R2(full drain)==R3(no drain)==195us refuted store-cost).
//   blocks 0..31  : FPS, BYTE-IDENTICAL chain to R3 (best measured).
//                   After the chain, the block JOINS its batch's KNN claim
//                   pool (coords from cbuf LDS, points from pts3 LDS).
//   blocks 32..127: 3 KNN blocks/batch. Waves CLAIM centers from a
//                   per-batch atomic counter, poll sentinel-validated
//                   words (0xFFFFFFFF = NaN, impossible for finite coords).
// Scan cache: (u32 d-bits, u32 idx) pairs compared on d-bits strict-< —
// bit-identical to the u64 key cache (per-lane visit order is ascending
// idx, so equal-d insertion order == idx tie-break; extraction/refill use
// the exact u64 lex key). ~15% less VALU than u64 selects.
// Deadlock-free: one-way dependency + guaranteed co-residency.
#define BB 32
#define NN 8192
#define KK 128
#define PP 32
#define IDX_COUNT (BB * KK * PP)      // 131072
#define XCHG_WORDS (BB * KK * 3)      // 12288 center words
#define CLEAR_WORDS (XCHG_WORDS + BB) // + 32 claim counters
#define KNN_PER_B 3
#define NBLK (BB + BB * KNN_PER_B)    // 128

// ---- DPP wave64 reductions (VALU-only) ------------------------------------
// row_shr:1/2/4/8 then row_bcast15/31; lane 63 holds the result.
#define DPP_RED_U64(v, CMP)                                                   \
    {                                                                         \
        _Pragma("unroll")                                                     \
        for (int s = 0; s < 6; ++s) {                                         \
            const int ctrl = (s == 0) ? 0x111 : (s == 1) ? 0x112 :            \
                             (s == 2) ? 0x114 : (s == 3) ? 0x118 :            \
                             (s == 4) ? 0x142 : 0x143;                        \
            unsigned lo = (unsigned)v, hi = (unsigned)(v >> 32);              \
            unsigned slo, shi;                                                \
            switch (ctrl) {                                                   \
            case 0x111:                                                       \
                slo = (unsigned)__builtin_amdgcn_update_dpp((int)lo, (int)lo, 0x111, 0xf, 0xf, false); \
                shi = (unsigned)__builtin_amdgcn_update_dpp((int)hi, (int)hi, 0x111, 0xf, 0xf, false); break; \
            case 0x112:                                                       \
                slo = (unsigned)__builtin_amdgcn_update_dpp((int)lo, (int)lo, 0x112, 0xf, 0xf, false); \
                shi = (unsigned)__builtin_amdgcn_update_dpp((int)hi, (int)hi, 0x112, 0xf, 0xf, false); break; \
            case 0x114:                                                       \
                slo = (unsigned)__builtin_amdgcn_update_dpp((int)lo, (int)lo, 0x114, 0xf, 0xf, false); \
                shi = (unsigned)__builtin_amdgcn_update_dpp((int)hi, (int)hi, 0x114, 0xf, 0xf, false); break; \
            case 0x118:                                                       \
                slo = (unsigned)__builtin_amdgcn_update_dpp((int)lo, (int)lo, 0x118, 0xf, 0xf, false); \
                shi = (unsigned)__builtin_amdgcn_update_dpp((int)hi, (int)hi, 0x118, 0xf, 0xf, false); break; \
            case 0x142:                                                       \
                slo = (unsigned)__builtin_amdgcn_update_dpp((int)lo, (int)lo, 0x142, 0xf, 0xf, false); \
                shi = (unsigned)__builtin_amdgcn_update_dpp((int)hi, (int)hi, 0x142, 0xf, 0xf, false); break; \
            default:                                                          \
                slo = (unsigned)__builtin_amdgcn_update_dpp((int)lo, (int)lo, 0x143, 0xf, 0xf, false); \
                shi = (unsigned)__builtin_amdgcn_update_dpp((int)hi, (int)hi, 0x143, 0xf, 0xf, false); break; \
            }                                                                 \
            const unsigned long long sv = ((unsigned long long)shi << 32) | slo; \
            if (sv CMP v) v = sv;                                             \
        }                                                                     \
    }

__device__ __forceinline__ unsigned long long readlane63_u64(unsigned long long v) {
    const unsigned lo = (unsigned)__builtin_amdgcn_readlane((int)(unsigned)v, 63);
    const unsigned hi = (unsigned)__builtin_amdgcn_readlane((int)(unsigned)(v >> 32), 63);
    return ((unsigned long long)hi << 32) | lo;
}

// Relaxed agent-scope word publish/poll. Finite-float bit patterns can never
// be 0xFFFFFFFF => sentinel self-validates each word; no ordering needed.
__device__ __forceinline__ void publish_word(unsigned* p, float v) {
    __hip_atomic_store(p, __float_as_uint(v), __ATOMIC_RELAXED,
                       __HIP_MEMORY_SCOPE_AGENT);
}
__device__ __forceinline__ float poll_word(const unsigned* p) {
    unsigned u = __hip_atomic_load(p, __ATOMIC_RELAXED, __HIP_MEMORY_SCOPE_AGENT);
    while (u == 0xFFFFFFFFu) {
        __builtin_amdgcn_s_sleep(8);   // ~512 cyc backoff
        u = __hip_atomic_load(p, __ATOMIC_RELAXED, __HIP_MEMORY_SCOPE_AGENT);
    }
    return __uint_as_float(u);
}

// Raw barrier with LDS-only drain (no vmcnt): publish stores stay in flight.
#define BAR_LDS() asm volatile("s_waitcnt lgkmcnt(0)\n\ts_barrier" ::: "memory")

// Dual-array sorted insert, compare on d-bits strict-< (see header comment
// for the bit-parity argument). 4 u32 cmps + 24 selects.
#define CACHE_INS2(dd, ii, d1, i1, d2, i2, d3, i3, d4, i4)              \
    {                                                                   \
        const bool c1 = (dd) < d1, c2 = (dd) < d2,                      \
                   c3 = (dd) < d3, c4 = (dd) < d4;                      \
        d4 = c3 ? d3 : (c4 ? (dd) : d4);  i4 = c3 ? i3 : (c4 ? (ii) : i4); \
        d3 = c2 ? d2 : (c3 ? (dd) : d3);  i3 = c2 ? i2 : (c3 ? (ii) : i3); \
        d2 = c1 ? d1 : (c2 ? (dd) : d2);  i2 = c1 ? i1 : (c2 ? (ii) : i2); \
        d1 = c1 ? (dd) : d1;              i1 = c1 ? (ii) : i1;          \
    }

// One center's exact KNN for one wave. SRC=0: float4(x,y,z,pp) LDS cloud;
// SRC=1: packed xyz LDS cloud (FPS block's pts3), pp computed on the fly.
template <int SRC>
__device__ __forceinline__ void knn_one_center(
    const float* __restrict__ ldsf, const int lane,
    const float cx, const float cy, const float cz,
    float* __restrict__ outp)
{
#pragma clang fp contract(off)
    const float cc = (cx * cx + cy * cy) + cz * cz;
    unsigned d1 = ~0u, i1 = ~0u, d2_ = ~0u, i2 = ~0u,
             d3 = ~0u, i3 = ~0u, d4 = ~0u, i4 = ~0u;
#pragma unroll 4
    for (int i = 0; i < 128; ++i) {
        const int idx = lane + i * 64;
        float qx, qy, qz, qw;
        if constexpr (SRC == 0) {
            const float4 q = ((const float4*)ldsf)[idx];
            qx = q.x; qy = q.y; qz = q.z; qw = q.w;
        } else {
            qx = ldsf[idx * 3 + 0]; qy = ldsf[idx * 3 + 1]; qz = ldsf[idx * 3 + 2];
            qw = (qx * qx + qy * qy) + qz * qz;
        }
        const float dot = (cx * qx + cy * qy) + cz * qz;
        float dd2 = (cc + qw) - (2.0f * dot);
        dd2 = dd2 + 0.0f;                                   // -0.0 -> +0.0
        unsigned u = __float_as_uint(dd2);
        u = (u & 0x80000000u) ? ~u : (u | 0x80000000u);     // ordered-uint
        CACHE_INS2(u, (unsigned)idx, d1, i1, d2_, i2, d3, i3, d4, i4);
    }

    float resv = 0.0f;
    for (int j = 0; j < PP; ++j) {
        unsigned long long r = ((unsigned long long)d1 << 32) | i1;
        DPP_RED_U64(r, <);                        // lane 63 authoritative
        const unsigned long long best = readlane63_u64(r);
        if (lane == j) resv = (float)(unsigned)(best & 0xFFFFFFFFu);
        if (((((unsigned long long)d1 << 32) | i1)) == best) {   // pop owner
            d1 = d2_; i1 = i2; d2_ = d3; i2 = i3; d3 = d4; i3 = i4;
            d4 = ~0u; i4 = ~0u;
        }
        if (d1 == ~0u) {                          // rare exact refill
            for (int i = 0; i < 128; ++i) {
                const int idx = lane + i * 64;
                float qx, qy, qz, qw;
                if constexpr (SRC == 0) {
                    const float4 q = ((const float4*)ldsf)[idx];
                    qx = q.x; qy = q.y; qz = q.z; qw = q.w;
                } else {
                    qx = ldsf[idx * 3 + 0]; qy = ldsf[idx * 3 + 1]; qz = ldsf[idx * 3 + 2];
                    qw = (qx * qx + qy * qy) + qz * qz;
                }
                const float dot = (cx * qx + cy * qy) + cz * qz;
                float dd2 = (cc + qw) - (2.0f * dot);
                dd2 = dd2 + 0.0f;
                unsigned u = __float_as_uint(dd2);
                u = (u & 0x80000000u) ? ~u : (u | 0x80000000u);
                const unsigned long long kk2 =
                    ((unsigned long long)u << 32) | (unsigned)idx;
                if (kk2 > best)
                    CACHE_INS2(u, (unsigned)idx, d1, i1, d2_, i2, d3, i3, d4, i4);
            }
        }
    }
    if (lane < PP) outp[lane] = resv;             // 128 B/wave
}

__global__ __launch_bounds__(1024) void clear_kernel(unsigned* __restrict__ xchg) {
    const int i = blockIdx.x * 1024 + threadIdx.x;
    if (i < XCHG_WORDS) xchg[i] = 0xFFFFFFFFu;       // center sentinels
    else if (i < CLEAR_WORDS) xchg[i] = 0u;          // claim counters
}

__global__ __launch_bounds__(512) void fused_kernel(
    const float* __restrict__ pts, float* __restrict__ out,
    unsigned* __restrict__ xchg)
{
#pragma clang fp contract(off)
    // 128 KiB raw LDS => hard 1 block/CU (residency: 128 blocks <= 256 CUs).
    __shared__ __align__(16) unsigned char smem_raw[131072];
    const int t = threadIdx.x;
    const int lane = t & 63, wid = t >> 6;
    unsigned* claims = xchg + XCHG_WORDS;

    if (blockIdx.x < BB) {
        // ---------------- FPS producer (chain identical to R3) -----------
        const int b = blockIdx.x;
        const float* p = pts + (size_t)b * NN * 3;
        float* pts3 = (float*)smem_raw;                        // 96 KB
        float* cbuf = (float*)(smem_raw + 98304);              // 1.5 KB
        unsigned long long* wkf =
            (unsigned long long*)(smem_raw + 98304 + 1536);    // [2][8]

        if (t == 0) {   // publish center 0 (= point 0) immediately
            unsigned* dst = xchg + (unsigned)b * KK * 3u;
            publish_word(dst + 0, p[0]);
            publish_word(dst + 1, p[1]);
            publish_word(dst + 2, p[2]);
        }

        float px[16], py[16], pz[16], mind[16];
#pragma unroll
        for (int i = 0; i < 16; ++i) {
            const int idx = t + i * 512;
            const float x = p[idx * 3 + 0], y = p[idx * 3 + 1], z = p[idx * 3 + 2];
            px[i] = x; py[i] = y; pz[i] = z; mind[i] = __builtin_inff();
            pts3[idx * 3 + 0] = x; pts3[idx * 3 + 1] = y; pts3[idx * 3 + 2] = z;
        }
        __syncthreads();

        float lx = pts3[0], ly = pts3[1], lz = pts3[2];
        if (t == 0) { cbuf[0] = lx; cbuf[1] = ly; cbuf[2] = lz; }

        for (int k = 0; k < KK - 1; ++k) {       // 127 serial steps
            float best = -1.0f; unsigned bidx = 0;
#pragma unroll
            for (int i = 0; i < 16; ++i) {
                const float dx = px[i] - lx, dy = py[i] - ly, dz = pz[i] - lz;
                const float d = (dx * dx + dy * dy) + dz * dz;
                const float m = mind[i] < d ? mind[i] : d;
                mind[i] = m;
                if (m > best) { best = m; bidx = (unsigned)(t + i * 512); }
            }
            union { float f; unsigned u; } cv; cv.f = best;   // best >= 0
            unsigned long long key = ((unsigned long long)cv.u << 32)
                                   | (0xFFFFFFFFu - bidx);    // low-idx tie-break
            DPP_RED_U64(key, >);                  // lane 63 authoritative
            if (lane == 63) wkf[(k & 1) * 8 + wid] = key;
            BAR_LDS();   // LDS-only drain: publish stores stay in flight
            unsigned long long w = wkf[(k & 1) * 8];
#pragma unroll
            for (int i = 1; i < 8; ++i) {
                const unsigned long long o = wkf[(k & 1) * 8 + i];
                if (o > w) w = o;
            }
            const unsigned last = 0xFFFFFFFFu - (unsigned)(w & 0xFFFFFFFFu);
            lx = pts3[last * 3 + 0];              // broadcast reads
            ly = pts3[last * 3 + 1];
            lz = pts3[last * 3 + 2];
            if (t == 0) {
                cbuf[(k + 1) * 3 + 0] = lx;
                cbuf[(k + 1) * 3 + 1] = ly;
                cbuf[(k + 1) * 3 + 2] = lz;
                unsigned* dst = xchg + ((unsigned)b * KK + (unsigned)(k + 1)) * 3u;
                publish_word(dst + 0, lx);        // fire-and-forget (relaxed)
                publish_word(dst + 1, ly);
                publish_word(dst + 2, lz);
            }
        }
        __syncthreads();
        if (t < KK * 3)
            out[IDX_COUNT + b * (KK * 3) + t] = cbuf[t];

        // ------- chain done: JOIN the claim pool for this batch ----------
        // Coords from cbuf (LDS), points from pts3 (LDS) — no polling, no
        // restaging. Adds 32 CUs exactly when the tail risk peaks.
        for (;;) {
            unsigned m = 0;
            if (lane == 0) m = atomicAdd(claims + b, 1u);
            m = (unsigned)__builtin_amdgcn_readfirstlane((int)m);
            if (m >= KK) break;
            const int c = (int)m;
            const float cx = cbuf[c * 3 + 0];
            const float cy = cbuf[c * 3 + 1];
            const float cz = cbuf[c * 3 + 2];
            knn_one_center<1>(pts3, lane, cx, cy, cz,
                              out + (size_t)(b * KK + c) * PP);
        }
    } else {
        // ------------------------- KNN consumer --------------------------
        const int blk = blockIdx.x - BB;          // 0..95
        const int b = blk / KNN_PER_B;            // 3 blocks/batch
        float4* sp = (float4*)smem_raw;           // 128 KB
        const float* p = pts + (size_t)b * NN * 3;
#pragma unroll
        for (int i = 0; i < 16; ++i) {
            const int idx = t + i * 512;
            const float x = p[idx * 3 + 0], y = p[idx * 3 + 1], z = p[idx * 3 + 2];
            sp[idx] = make_float4(x, y, z, (x * x + y * y) + z * z);
        }
        __syncthreads();   // only barrier; afterwards waves run independently

        for (;;) {
            unsigned m = 0;
            if (lane == 0) m = atomicAdd(claims + b, 1u);
            m = (unsigned)__builtin_amdgcn_readfirstlane((int)m);
            if (m >= KK) break;
            const int c = (int)m;

            const unsigned* src = xchg + ((unsigned)b * KK + (unsigned)c) * 3u;
            const float cx = poll_word(src + 0);
            const float cy = poll_word(src + 1);
            const float cz = poll_word(src + 2);
            knn_one_center<0>((const float*)sp, lane, cx, cy, cz,
                              out + (size_t)(b * KK + c) * PP);
        }
    }
}

// ------------------------- fallback (ws too small) -------------------------
__global__ __launch_bounds__(512) void fps_kernel(
    const float* __restrict__ pts, float* __restrict__ out)
{
#pragma clang fp contract(off)
    const int b = blockIdx.x;
    const int t = threadIdx.x;
    const float* p = pts + (size_t)b * NN * 3;

    __shared__ float pts3[NN * 3];
    __shared__ float cbuf[KK * 3];
    __shared__ unsigned long long wk[2][8];

    float px[16], py[16], pz[16], mind[16];
#pragma unroll
    for (int i = 0; i < 16; ++i) {
        const int idx = t + i * 512;
        const float x = p[idx * 3 + 0], y = p[idx * 3 + 1], z = p[idx * 3 + 2];
        px[i] = x; py[i] = y; pz[i] = z; mind[i] = __builtin_inff();
        pts3[idx * 3 + 0] = x; pts3[idx * 3 + 1] = y; pts3[idx * 3 + 2] = z;
    }
    __syncthreads();

    float lx = pts3[0], ly = pts3[1], lz = pts3[2];
    if (t == 0) { cbuf[0] = lx; cbuf[1] = ly; cbuf[2] = lz; }
    const int lane = t & 63, wid = t >> 6;

    for (int k = 0; k < KK - 1; ++k) {
        float best = -1.0f; unsigned bidx = 0;
#pragma unroll
        for (int i = 0; i < 16; ++i) {
            const float dx = px[i] - lx, dy = py[i] - ly, dz = pz[i] - lz;
            const float d = (dx * dx + dy * dy) + dz * dz;
            const float m = mind[i] < d ? mind[i] : d;
            mind[i] = m;
            if (m > best) { best = m; bidx = (unsigned)(t + i * 512); }
        }
        union { float f; unsigned u; } cv; cv.f = best;
        unsigned long long key = ((unsigned long long)cv.u << 32)
                               | (0xFFFFFFFFu - bidx);
        DPP_RED_U64(key, >);
        if (lane == 63) wk[k & 1][wid] = key;
        __syncthreads();
        unsigned long long w = wk[k & 1][0];
#pragma unroll
        for (int i = 1; i < 8; ++i) {
            const unsigned long long o = wk[k & 1][i];
            if (o > w) w = o;
        }
        const unsigned last = 0xFFFFFFFFu - (unsigned)(w & 0xFFFFFFFFu);
        lx = pts3[last * 3 + 0];
        ly = pts3[last * 3 + 1];
        lz = pts3[last * 3 + 2];
        if (t == 0) {
            cbuf[(k + 1) * 3 + 0] = lx;
            cbuf[(k + 1) * 3 + 1] = ly;
            cbuf[(k + 1) * 3 + 2] = lz;
        }
    }
    __syncthreads();
    if (t < KK * 3)
        out[IDX_COUNT + b * (KK * 3) + t] = cbuf[t];
}

__global__ __launch_bounds__(1024) void knn_kernel(
    const float* __restrict__ pts, float* __restrict__ out)
{
#pragma clang fp contract(off)
    const int t = threadIdx.x, lane = t & 63, wid = t >> 6;
    const int blk = blockIdx.x;
    const int b = blk >> 3;
    const int bk = b * KK + (blk & 7) * 16 + wid;

    __shared__ float4 sp[NN];
    const float* p = pts + (size_t)b * NN * 3;
#pragma unroll
    for (int i = 0; i < 8; ++i) {
        const int idx = t + i * 1024;
        const float x = p[idx * 3 + 0], y = p[idx * 3 + 1], z = p[idx * 3 + 2];
        sp[idx] = make_float4(x, y, z, (x * x + y * y) + z * z);
    }

    const float cx = out[IDX_COUNT + bk * 3 + 0];
    const float cy = out[IDX_COUNT + bk * 3 + 1];
    const float cz = out[IDX_COUNT + bk * 3 + 2];
    __syncthreads();

    knn_one_center<0>((const float*)sp, lane, cx, cy, cz,
                      out + (size_t)bk * PP);
}

extern "C" void kernel_launch(void* const* d_in, const int* in_sizes, int n_in,
                              void* d_out, int out_size, void* d_ws, size_t ws_size,
                              hipStream_t stream) {
    const float* pts = (const float*)d_in[0];
    float* out = (float*)d_out;   // f32: [idx 131072 | centers 12288]

    if (ws_size >= (size_t)(CLEAR_WORDS * 4)) {
        clear_kernel<<<(CLEAR_WORDS + 1023) / 1024, 1024, 0, stream>>>(
            (unsigned*)d_ws);
        fused_kernel<<<NBLK, 512, 0, stream>>>(pts, out, (unsigned*)d_ws);
    } else {
        fps_kernel<<<BB, 512, 0, stream>>>(pts, out);
        knn_kernel<<<BB * 8, 1024, 0, stream>>>(pts, out);
    }
}